// Round 18
// baseline (61.488 us; speedup 1.0000x reference)
//
#include <hip/hip_runtime.h>
#include <hip/hip_bf16.h>

#define IN_DIM 128
#define OUT_DIM 128
#define NHEAD 8
#define HD 16
#define BB 8
#define NN 1024
#define LOG2E 1.44269504f

typedef unsigned long long u64;
typedef float f32x4 __attribute__((ext_vector_type(4)));
typedef float f32x2 __attribute__((ext_vector_type(2)));
typedef short bf16x8 __attribute__((ext_vector_type(8)));

__device__ __forceinline__ f32x2 pk_mul(f32x2 a, f32x2 b) {
    f32x2 r;
    asm("v_pk_mul_f32 %0, %1, %2" : "=v"(r) : "v"(a), "v"(b));
    return r;
}
__device__ __forceinline__ f32x2 pk_add(f32x2 a, f32x2 b) {
    f32x2 r;
    asm("v_pk_add_f32 %0, %1, %2" : "=v"(r) : "v"(a), "v"(b));
    return r;
}

// j-permutation (consistent across whT, sj_g, bits_t; j-sums are invariant):
//   p(j) = (j>>8)*256 + (j&3)*64 + ((j>>2)&63);  bits_t word = pj>>5, bit = pj&31.

// ---- Kernel P: pack adj -> transposed u32 masks  +  w1/w2 transpose+cvt ----
__global__ __launch_bounds__(256) void k_pack(const int* __restrict__ adj,
                                              unsigned* __restrict__ bits_t,
                                              const float* __restrict__ w1,
                                              const float* __restrict__ w2,
                                              unsigned short* __restrict__ w1T,
                                              unsigned short* __restrict__ w2T) {
    __shared__ float tile[32][33];
    int t = threadIdx.x;
    if (blockIdx.x < 2048) {
        int lane = t & 63;
        int wave_id = blockIdx.x * 4 + (t >> 6);
        int b = wave_id >> 10, i = wave_id & 1023;
        const int4* rowp = (const int4*)(adj + ((size_t)(b * 1024 + i)) * 1024);
        int4 v0 = rowp[lane];
        int4 v1 = rowp[64 + lane];
        int4 v2 = rowp[128 + lane];
        int4 v3 = rowp[192 + lane];
        u64 B0x = __ballot(v0.x != 0), B0y = __ballot(v0.y != 0), B0z = __ballot(v0.z != 0), B0w = __ballot(v0.w != 0);
        u64 B1x = __ballot(v1.x != 0), B1y = __ballot(v1.y != 0), B1z = __ballot(v1.z != 0), B1w = __ballot(v1.w != 0);
        u64 B2x = __ballot(v2.x != 0), B2y = __ballot(v2.y != 0), B2z = __ballot(v2.z != 0), B2w = __ballot(v2.w != 0);
        u64 B3x = __ballot(v3.x != 0), B3y = __ballot(v3.y != 0), B3z = __ballot(v3.z != 0), B3w = __ballot(v3.w != 0);
        if (lane == 0) {
            unsigned* dst = bits_t + (size_t)b * 32 * 1024 + i;
#define STW(ch, c, B) \
            dst[((ch) * 8 + (c) * 2 + 0) * 1024] = (unsigned)(B); \
            dst[((ch) * 8 + (c) * 2 + 1) * 1024] = (unsigned)((B) >> 32);
            STW(0, 0, B0x) STW(0, 1, B0y) STW(0, 2, B0z) STW(0, 3, B0w)
            STW(1, 0, B1x) STW(1, 1, B1y) STW(1, 2, B1z) STW(1, 3, B1w)
            STW(2, 0, B2x) STW(2, 1, B2y) STW(2, 2, B2z) STW(2, 3, B2w)
            STW(3, 0, B3x) STW(3, 1, B3y) STW(3, 2, B3z) STW(3, 3, B3w)
#undef STW
        }
    } else {
        int blk = blockIdx.x - 2048;
        const float* src; unsigned short* dst; int R, C;
        if (blk < 32) { src = w1; dst = w1T; R = 128; C = 256; }
        else          { src = w2; dst = w2T; R = 256; C = 128; blk -= 32; }
        int tpr = C >> 5;
        int tr = blk / tpr, tc = blk - tr * tpr;
        int r0 = tr << 5, c0 = tc << 5;
        int lr = t >> 5, lc = t & 31;
#pragma unroll
        for (int p = 0; p < 4; ++p)
            tile[lr + p * 8][lc] = src[(size_t)(r0 + lr + p * 8) * C + c0 + lc];
        __syncthreads();
#pragma unroll
        for (int p = 0; p < 4; ++p) {
            __hip_bfloat16 bv = __float2bfloat16(tile[lc][lr + p * 8]);
            dst[(size_t)(c0 + lr + p * 8) * R + r0 + lc] = *(unsigned short*)&bv;
        }
    }
}

// ---- Kernel A: Wh -> whT bf16 (permuted j) + si/sj (x log2e) — r13 exact ---
__global__ __launch_bounds__(256) void k_wh(
    const float* __restrict__ hin, const float* __restrict__ W,
    const float* __restrict__ a,
    unsigned short* __restrict__ whT, float* __restrict__ si_g,
    float* __restrict__ sj_g)
{
    extern __shared__ float smem[];
    float* h_s  = smem;             // 32 * 132
    float* wt_s = smem + 32 * 132;  // 128 * 132
    int t = threadIdx.x;
    int blk = blockIdx.x;
    int b = blk >> 5;
    int ntile = blk & 31;
    const float* hrow = hin + ((size_t)b * NN + ntile * 32) * IN_DIM;

#pragma unroll
    for (int it = 0; it < 4; ++it) {
        int g = t + 256 * it;
        int row = g >> 5, c4 = g & 31;
        float4 v = ((const float4*)hrow)[g];
        *(float4*)&h_s[row * 132 + c4 * 4] = v;
    }
    for (int g = t; g < (NHEAD * IN_DIM * HD) / 4; g += 256) {
        int hh = g >> 9;
        int rem = g & 511;
        int i = rem >> 2, d4 = rem & 3;
        float4 v = ((const float4*)W)[g];
        wt_s[(hh * 16 + d4 * 4 + 0) * 132 + i] = v.x;
        wt_s[(hh * 16 + d4 * 4 + 1) * 132 + i] = v.y;
        wt_s[(hh * 16 + d4 * 4 + 2) * 132 + i] = v.z;
        wt_s[(hh * 16 + d4 * 4 + 3) * 132 + i] = v.w;
    }
    __syncthreads();

    int d4 = t & 3;
    int hq = (t >> 2) & 7;
    int ngrp = t >> 5;
    float acc[4][4];
#pragma unroll
    for (int q = 0; q < 4; ++q)
#pragma unroll
        for (int dd = 0; dd < 4; ++dd) acc[q][dd] = 0.f;

    for (int i4 = 0; i4 < 32; ++i4) {
        float4 wr[4], hv[4];
#pragma unroll
        for (int dd = 0; dd < 4; ++dd)
            wr[dd] = *(const float4*)&wt_s[(hq * 16 + d4 * 4 + dd) * 132 + i4 * 4];
#pragma unroll
        for (int q = 0; q < 4; ++q)
            hv[q] = *(const float4*)&h_s[(ngrp * 4 + q) * 132 + i4 * 4];
#pragma unroll
        for (int q = 0; q < 4; ++q)
#pragma unroll
            for (int dd = 0; dd < 4; ++dd)
                acc[q][dd] += hv[q].x * wr[dd].x + hv[q].y * wr[dd].y +
                              hv[q].z * wr[dd].z + hv[q].w * wr[dd].w;
    }

    int bh = b * NHEAD + hq;
    int rowbase = ntile * 32 + ngrp * 4;
    int p0 = ((rowbase >> 8) << 8) | ((rowbase >> 2) & 63);

    float asrc[4], adst[4];
#pragma unroll
    for (int dd = 0; dd < 4; ++dd) {
        asrc[dd] = a[hq * 32 + d4 * 4 + dd];
        adst[dd] = a[hq * 32 + 16 + d4 * 4 + dd];
    }
#pragma unroll
    for (int q = 0; q < 4; ++q) {
        float psi = acc[q][0] * asrc[0] + acc[q][1] * asrc[1] + acc[q][2] * asrc[2] + acc[q][3] * asrc[3];
        float psj = acc[q][0] * adst[0] + acc[q][1] * adst[1] + acc[q][2] * adst[2] + acc[q][3] * adst[3];
        psi += __shfl_xor(psi, 1); psi += __shfl_xor(psi, 2);
        psj += __shfl_xor(psj, 1); psj += __shfl_xor(psj, 2);
        if (d4 == 0) {
            si_g[(size_t)bh * NN + rowbase + q] = psi * LOG2E;
            sj_g[(size_t)bh * NN + p0 + q * 64] = psj * LOG2E;
        }
    }

#pragma unroll
    for (int dd = 0; dd < 4; ++dd) {
        unsigned u0, u1;
        asm("v_cvt_pk_bf16_f32 %0, %1, %2" : "=v"(u0) : "v"(acc[0][dd]), "v"(acc[1][dd]));
        asm("v_cvt_pk_bf16_f32 %0, %1, %2" : "=v"(u1) : "v"(acc[2][dd]), "v"(acc[3][dd]));
        size_t basei = (size_t)(bh * 16 + d4 * 4 + dd) * 1024 + p0;
        whT[basei]       = (unsigned short)(u0 & 0xffff);
        whT[basei + 64]  = (unsigned short)(u0 >> 16);
        whT[basei + 128] = (unsigned short)(u1 & 0xffff);
        whT[basei + 192] = (unsigned short)(u1 >> 16);
    }
}

// ---- Kernel B: attention per (b,h) — exp-free softmax, packed-f32 math -----
// v_pk_mul_f32 halves the 16 muls; v_pk_add_f32 halves the lsum adds.
// Same operand values and pairwise-tree association as r15 -> same numerics.
__global__ __launch_bounds__(512, 3) void k_attn(
    const unsigned short* __restrict__ whT,
    const unsigned* __restrict__ bits_t,
    const float* __restrict__ si_g, const float* __restrict__ sj_g,
    float* __restrict__ hh)
{
    __shared__ __align__(16) unsigned short whT_s[16 * 1032];
    __shared__ __align__(16) float ejp_s[NN];
    __shared__ __align__(16) float ejn_s[NN];
    int t = threadIdx.x;
    int blk = blockIdx.x;
    int part = blk & 7;
    int bh = blk >> 3;
    int hq = bh & 7, b = bh >> 3;
    int blkrow = part * 128;

    {
        const uint4* src = (const uint4*)(whT + (size_t)bh * 16 * 1024);
#pragma unroll
        for (int it = 0; it < 4; ++it) {
            int g = t + 512 * it;
            int d = g >> 7, c8 = g & 127;
            uint4 v = src[g];
            *(uint4*)&whT_s[d * 1032 + c8 * 8] = v;
        }
#pragma unroll
        for (int jt = 0; jt < 2; ++jt) {
            int j = t + jt * 512;
            float sjv = sj_g[(size_t)bh * NN + j];
            float ep, en;
            asm("v_exp_f32 %0, %1" : "=v"(ep) : "v"(sjv));
            asm("v_exp_f32 %0, %1" : "=v"(en) : "v"(0.2f * sjv));
            ejp_s[j] = ep;
            ejn_s[j] = en;
        }
    }
    __syncthreads();

    int wv = t >> 6, lane = t & 63;
    int lo16 = lane & 15, g = lane >> 4;
    int row = blkrow + wv * 16 + lo16;
    float siL = si_g[(size_t)bh * NN + row];
    float esip, esin;
    asm("v_exp_f32 %0, %1" : "=v"(esip) : "v"(siL));
    asm("v_exp_f32 %0, %1" : "=v"(esin) : "v"(0.2f * siL));
    const unsigned* mcol = bits_t + (size_t)b * 32 * 1024 + row;

    const unsigned short* wbase = &whT_s[lo16 * 1032 + g * 8];
    const float* pbase = &ejp_s[g * 8];
    const float* nbase = &ejn_s[g * 8];

    f32x2 esip2 = {esip, esip};
    f32x2 esin2 = {esin, esin};

    f32x4 acc = {0.f, 0.f, 0.f, 0.f};
    f32x2 lsum2 = {0.f, 0.f};
    unsigned m = mcol[0];
#pragma unroll 4
    for (int kt = 0; kt < 32; ++kt) {
        unsigned m_next = (kt < 31) ? mcol[(size_t)(kt + 1) * 1024] : 0u;
        bf16x8 bfrag = *(const bf16x8*)&wbase[kt * 32];
        float4 pa = *(const float4*)&pbase[kt * 32];
        float4 pb = *(const float4*)&pbase[kt * 32 + 4];
        float4 na = *(const float4*)&nbase[kt * 32];
        float4 nb = *(const float4*)&nbase[kt * 32 + 4];
        unsigned mm = m >> (g * 8);

        f32x2 t01 = pk_mul(esip2, (f32x2){pa.x, pa.y});
        f32x2 u01 = pk_mul(esin2, (f32x2){na.x, na.y});
        f32x2 t23 = pk_mul(esip2, (f32x2){pa.z, pa.w});
        f32x2 u23 = pk_mul(esin2, (f32x2){na.z, na.w});
        f32x2 t45 = pk_mul(esip2, (f32x2){pb.x, pb.y});
        f32x2 u45 = pk_mul(esin2, (f32x2){nb.x, nb.y});
        f32x2 t67 = pk_mul(esip2, (f32x2){pb.z, pb.w});
        f32x2 u67 = pk_mul(esin2, (f32x2){nb.z, nb.w});

        float q0 = fmaxf(t01[0], u01[0]); q0 = (mm & 1u)   ? q0 : 0.f;
        float q1 = fmaxf(t01[1], u01[1]); q1 = (mm & 2u)   ? q1 : 0.f;
        float q2 = fmaxf(t23[0], u23[0]); q2 = (mm & 4u)   ? q2 : 0.f;
        float q3 = fmaxf(t23[1], u23[1]); q3 = (mm & 8u)   ? q3 : 0.f;
        float q4 = fmaxf(t45[0], u45[0]); q4 = (mm & 16u)  ? q4 : 0.f;
        float q5 = fmaxf(t45[1], u45[1]); q5 = (mm & 32u)  ? q5 : 0.f;
        float q6 = fmaxf(t67[0], u67[0]); q6 = (mm & 64u)  ? q6 : 0.f;
        float q7 = fmaxf(t67[1], u67[1]); q7 = (mm & 128u) ? q7 : 0.f;

        f32x2 s0 = pk_add((f32x2){q0, q1}, (f32x2){q2, q3});
        f32x2 s1 = pk_add((f32x2){q4, q5}, (f32x2){q6, q7});
        lsum2 = pk_add(lsum2, pk_add(s0, s1));

        union { bf16x8 v; __hip_bfloat16 h[8]; } af;
        af.h[0] = __float2bfloat16(q0);
        af.h[1] = __float2bfloat16(q1);
        af.h[2] = __float2bfloat16(q2);
        af.h[3] = __float2bfloat16(q3);
        af.h[4] = __float2bfloat16(q4);
        af.h[5] = __float2bfloat16(q5);
        af.h[6] = __float2bfloat16(q6);
        af.h[7] = __float2bfloat16(q7);
        acc = __builtin_amdgcn_mfma_f32_16x16x32_bf16(af.v, bfrag, acc, 0, 0, 0);
        m = m_next;
    }

    float lsum = lsum2[0] + lsum2[1];
    lsum += __shfl_xor(lsum, 16);
    lsum += __shfl_xor(lsum, 32);

    float* obase = hh + ((size_t)b * NN + blkrow + wv * 16) * OUT_DIM + hq * HD + lo16;
#pragma unroll
    for (int q = 0; q < 4; ++q) {
        float ls = __shfl(lsum, 4 * g + q);
        float r = (ls > 0.f) ? 1.0f / ls : 0.f;
        obase[(size_t)(4 * g + q) * OUT_DIM] = acc[q] * r;
    }
}

// -------- Kernel C: LN1 + FFN (MFMA bf16) + LN2 — r6/r8 exact ----------
__global__ __launch_bounds__(512, 1) void k_ffn(const float* __restrict__ hhs,
                                                const float* __restrict__ hin,
                                                const float* __restrict__ g1,
                                                const float* __restrict__ bt1,
                                                const unsigned short* __restrict__ w1T,
                                                const float* __restrict__ bb1,
                                                const unsigned short* __restrict__ w2T,
                                                const float* __restrict__ bb2,
                                                const float* __restrict__ g2,
                                                const float* __restrict__ bt2,
                                                float* __restrict__ out) {
    __shared__ float xc_f[32][128];
    __shared__ float y_f[32][132];
    __shared__ __align__(16) unsigned short xc_bf[32 * 128];
    __shared__ __align__(16) unsigned short hid_bf[32 * 256];

    int t = threadIdx.x;
    int R0 = blockIdx.x * 32;
    int wv = t >> 6, lane = t & 63;
    int lo = lane & 15, g = lane >> 4;

    bf16x8 b1f[2][4];
#pragma unroll
    for (int jt = 0; jt < 2; ++jt) {
        int n = (wv * 2 + jt) * 16 + lo;
#pragma unroll
        for (int kt = 0; kt < 4; ++kt)
            b1f[jt][kt] = *(const bf16x8*)&w1T[(size_t)n * 128 + kt * 32 + g * 8];
    }
    bf16x8 b2f[8];
    {
        int n = wv * 16 + lo;
#pragma unroll
        for (int kt = 0; kt < 8; ++kt)
            b2f[kt] = *(const bf16x8*)&w2T[(size_t)n * 256 + kt * 32 + g * 8];
    }
    float b1v[2];
    b1v[0] = bb1[(wv * 2 + 0) * 16 + lo];
    b1v[1] = bb1[(wv * 2 + 1) * 16 + lo];
    float b2v = bb2[wv * 16 + lo];

    {
        int r = t >> 4, c = t & 15;
        size_t row = (size_t)(R0 + r) * 128;
        float4 ha = *(const float4*)&hhs[row + c * 8];
        float4 hb = *(const float4*)&hhs[row + c * 8 + 4];
        float4 ia = *(const float4*)&hin[row + c * 8];
        float4 ib = *(const float4*)&hin[row + c * 8 + 4];
        float x[8] = {ha.x + ia.x, ha.y + ia.y, ha.z + ia.z, ha.w + ia.w,
                      hb.x + ib.x, hb.y + ib.y, hb.z + ib.z, hb.w + ib.w};
        float s = 0.f, s2 = 0.f;
#pragma unroll
        for (int j = 0; j < 8; ++j) { s += x[j]; s2 += x[j] * x[j]; }
#pragma unroll
        for (int off = 8; off > 0; off >>= 1) {
            s += __shfl_xor(s, off);
            s2 += __shfl_xor(s2, off);
        }
        float mu = s * (1.f / 128.f);
        float var = s2 * (1.f / 128.f) - mu * mu;
        float rs = rsqrtf(var + 1e-5f);
        float4 ga = *(const float4*)&g1[c * 8], gb = *(const float4*)&g1[c * 8 + 4];
        float4 ba = *(const float4*)&bt1[c * 8], bb = *(const float4*)&bt1[c * 8 + 4];
        float gg[8] = {ga.x, ga.y, ga.z, ga.w, gb.x, gb.y, gb.z, gb.w};
        float bbv[8] = {ba.x, ba.y, ba.z, ba.w, bb.x, bb.y, bb.z, bb.w};
        float xo[8];
#pragma unroll
        for (int j = 0; j < 8; ++j) xo[j] = (x[j] - mu) * rs * gg[j] + bbv[j];
        *(float4*)&xc_f[r][c * 8]     = make_float4(xo[0], xo[1], xo[2], xo[3]);
        *(float4*)&xc_f[r][c * 8 + 4] = make_float4(xo[4], xo[5], xo[6], xo[7]);
        union { uint4 v; unsigned u[4]; } pk;
#pragma unroll
        for (int q = 0; q < 4; ++q)
            asm("v_cvt_pk_bf16_f32 %0, %1, %2" : "=v"(pk.u[q]) : "v"(xo[2 * q]), "v"(xo[2 * q + 1]));
        int byte = (r * 256 + c * 16) ^ ((r & 7) << 4);
        *(uint4*)((char*)xc_bf + byte) = pk.v;
    }
    __syncthreads();

    {
        bf16x8 af[2][4];
#pragma unroll
        for (int mt = 0; mt < 2; ++mt) {
            int m = mt * 16 + lo;
#pragma unroll
            for (int kt = 0; kt < 4; ++kt) {
                int byte = (m * 256 + kt * 64 + g * 16) ^ ((m & 7) << 4);
                af[mt][kt] = *(const bf16x8*)((const char*)xc_bf + byte);
            }
        }
#pragma unroll
        for (int mt = 0; mt < 2; ++mt)
#pragma unroll
            for (int jt = 0; jt < 2; ++jt) {
                f32x4 acc = {0.f, 0.f, 0.f, 0.f};
#pragma unroll
                for (int kt = 0; kt < 4; ++kt)
                    acc = __builtin_amdgcn_mfma_f32_16x16x32_bf16(af[mt][kt], b1f[jt][kt], acc, 0, 0, 0);
                int n = (wv * 2 + jt) * 16 + lo;
#pragma unroll
                for (int q = 0; q < 4; ++q) {
                    float hv = fmaxf(acc[q] + b1v[jt], 0.f);
                    int m = mt * 16 + 4 * g + q;
                    int byte = (m * 512 + n * 2) ^ ((m & 7) << 4);
                    __hip_bfloat16 bv = __float2bfloat16(hv);
                    *(unsigned short*)((char*)hid_bf + byte) = *(unsigned short*)&bv;
                }
            }
    }
    __syncthreads();

    {
        f32x4 acc2[2] = {{0.f, 0.f, 0.f, 0.f}, {0.f, 0.f, 0.f, 0.f}};
#pragma unroll
        for (int mt = 0; mt < 2; ++mt) {
            int m = mt * 16 + lo;
#pragma unroll
            for (int kt = 0; kt < 8; ++kt) {
                int byte = (m * 512 + kt * 64 + g * 16) ^ ((m & 7) << 4);
                bf16x8 a = *(const bf16x8*)((const char*)hid_bf + byte);
                acc2[mt] = __builtin_amdgcn_mfma_f32_16x16x32_bf16(a, b2f[kt], acc2[mt], 0, 0, 0);
            }
        }
        int n = wv * 16 + lo;
#pragma unroll
        for (int mt = 0; mt < 2; ++mt)
#pragma unroll
            for (int q = 0; q < 4; ++q)
                y_f[mt * 16 + 4 * g + q][n] = acc2[mt][q] + b2v;
    }
    __syncthreads();

    {
        int r = t >> 4, c = t & 15;
        float xv[8];
        float s = 0.f, s2 = 0.f;
#pragma unroll
        for (int j = 0; j < 8; ++j) {
            float v = xc_f[r][c * 8 + j] + y_f[r][c * 8 + j];
            xv[j] = v; s += v; s2 += v * v;
        }
#pragma unroll
        for (int off = 8; off > 0; off >>= 1) {
            s += __shfl_xor(s, off);
            s2 += __shfl_xor(s2, off);
        }
        float mu = s * (1.f / 128.f);
        float var = s2 * (1.f / 128.f) - mu * mu;
        float rs = rsqrtf(var + 1e-5f);
        float4 ga = *(const float4*)&g2[c * 8], gb = *(const float4*)&g2[c * 8 + 4];
        float4 ba = *(const float4*)&bt2[c * 8], bb = *(const float4*)&bt2[c * 8 + 4];
        float o[8] = {(xv[0] - mu) * rs * ga.x + ba.x, (xv[1] - mu) * rs * ga.y + ba.y,
                      (xv[2] - mu) * rs * ga.z + ba.z, (xv[3] - mu) * rs * ga.w + ba.w,
                      (xv[4] - mu) * rs * gb.x + bb.x, (xv[5] - mu) * rs * gb.y + bb.y,
                      (xv[6] - mu) * rs * gb.z + bb.z, (xv[7] - mu) * rs * gb.w + bb.w};
        size_t row = (size_t)(R0 + r) * 128;
        *(float4*)&out[row + c * 8]     = make_float4(o[0], o[1], o[2], o[3]);
        *(float4*)&out[row + c * 8 + 4] = make_float4(o[4], o[5], o[6], o[7]);
    }
}

extern "C" void kernel_launch(void* const* d_in, const int* in_sizes, int n_in,
                              void* d_out, int out_size, void* d_ws, size_t ws_size,
                              hipStream_t stream) {
    const float* hin  = (const float*)d_in[0];
    const int*   adj  = (const int*)d_in[1];
    const float* W    = (const float*)d_in[2];
    const float* a    = (const float*)d_in[3];
    const float* ln1g = (const float*)d_in[4];
    const float* ln1b = (const float*)d_in[5];
    const float* w1   = (const float*)d_in[6];
    const float* b1   = (const float*)d_in[7];
    const float* w2   = (const float*)d_in[8];
    const float* b2   = (const float*)d_in[9];
    const float* ln2g = (const float*)d_in[10];
    const float* ln2b = (const float*)d_in[11];
    float* out = (float*)d_out;

    unsigned* bits_t    = (unsigned*)d_ws;                                         // 1 MB
    unsigned short* whT = (unsigned short*)((char*)d_ws + (1u << 20));             // 2 MB
    float* si_g         = (float*)((char*)d_ws + (3u << 20));                      // 256 KB
    float* sj_g         = (float*)((char*)d_ws + (3u << 20) + (256u << 10));       // 256 KB
    float* hh           = (float*)((char*)d_ws + (3u << 20) + (512u << 10));       // 4 MB
    unsigned short* w1T = (unsigned short*)((char*)d_ws + (7u << 20) + (512u << 10));        // 64 KB
    unsigned short* w2T = (unsigned short*)((char*)d_ws + (7u << 20) + (512u << 10) + 65536);// 64 KB

    k_pack<<<2112, 256, 0, stream>>>(adj, bits_t, w1, w2, w1T, w2T);
    k_wh<<<BB * 32, 256, (32 * 132 + 128 * 132) * sizeof(float), stream>>>(hin, W, a, whT, si_g, sj_g);
    k_attn<<<BB * NHEAD * 8, 512, 0, stream>>>(whT, bits_t, si_g, sj_g, hh);
    k_ffn<<<BB * NN / 32, 512, 0, stream>>>(hh, hin, ln1g, ln1b, w1T, b1, w2T, b2, ln2g, ln2b, out);
}

// Round 19
// 56.319 us; speedup vs baseline: 1.0918x; 1.0918x over previous
//
#include <hip/hip_runtime.h>
#include <hip/hip_bf16.h>

#define IN_DIM 128
#define OUT_DIM 128
#define NHEAD 8
#define HD 16
#define BB 8
#define NN 1024
#define LOG2E 1.44269504f

typedef unsigned long long u64;
typedef float f32x4 __attribute__((ext_vector_type(4)));
typedef short bf16x8 __attribute__((ext_vector_type(8)));

// j-permutation (consistent across whT, sj_g, bits_t; j-sums are invariant):
//   p(j) = (j>>8)*256 + (j&3)*64 + ((j>>2)&63);  bits_t word = pj>>5, bit = pj&31.

// ---- Kernel P: pack adj -> transposed u32 masks  +  w1/w2 transpose+cvt ----
__global__ __launch_bounds__(256) void k_pack(const int* __restrict__ adj,
                                              unsigned* __restrict__ bits_t,
                                              const float* __restrict__ w1,
                                              const float* __restrict__ w2,
                                              unsigned short* __restrict__ w1T,
                                              unsigned short* __restrict__ w2T) {
    __shared__ float tile[32][33];
    int t = threadIdx.x;
    if (blockIdx.x < 2048) {
        int lane = t & 63;
        int wave_id = blockIdx.x * 4 + (t >> 6);
        int b = wave_id >> 10, i = wave_id & 1023;
        const int4* rowp = (const int4*)(adj + ((size_t)(b * 1024 + i)) * 1024);
        int4 v0 = rowp[lane];
        int4 v1 = rowp[64 + lane];
        int4 v2 = rowp[128 + lane];
        int4 v3 = rowp[192 + lane];
        u64 B0x = __ballot(v0.x != 0), B0y = __ballot(v0.y != 0), B0z = __ballot(v0.z != 0), B0w = __ballot(v0.w != 0);
        u64 B1x = __ballot(v1.x != 0), B1y = __ballot(v1.y != 0), B1z = __ballot(v1.z != 0), B1w = __ballot(v1.w != 0);
        u64 B2x = __ballot(v2.x != 0), B2y = __ballot(v2.y != 0), B2z = __ballot(v2.z != 0), B2w = __ballot(v2.w != 0);
        u64 B3x = __ballot(v3.x != 0), B3y = __ballot(v3.y != 0), B3z = __ballot(v3.z != 0), B3w = __ballot(v3.w != 0);
        if (lane == 0) {
            unsigned* dst = bits_t + (size_t)b * 32 * 1024 + i;
#define STW(ch, c, B) \
            dst[((ch) * 8 + (c) * 2 + 0) * 1024] = (unsigned)(B); \
            dst[((ch) * 8 + (c) * 2 + 1) * 1024] = (unsigned)((B) >> 32);
            STW(0, 0, B0x) STW(0, 1, B0y) STW(0, 2, B0z) STW(0, 3, B0w)
            STW(1, 0, B1x) STW(1, 1, B1y) STW(1, 2, B1z) STW(1, 3, B1w)
            STW(2, 0, B2x) STW(2, 1, B2y) STW(2, 2, B2z) STW(2, 3, B2w)
            STW(3, 0, B3x) STW(3, 1, B3y) STW(3, 2, B3z) STW(3, 3, B3w)
#undef STW
        }
    } else {
        int blk = blockIdx.x - 2048;
        const float* src; unsigned short* dst; int R, C;
        if (blk < 32) { src = w1; dst = w1T; R = 128; C = 256; }
        else          { src = w2; dst = w2T; R = 256; C = 128; blk -= 32; }
        int tpr = C >> 5;
        int tr = blk / tpr, tc = blk - tr * tpr;
        int r0 = tr << 5, c0 = tc << 5;
        int lr = t >> 5, lc = t & 31;
#pragma unroll
        for (int p = 0; p < 4; ++p)
            tile[lr + p * 8][lc] = src[(size_t)(r0 + lr + p * 8) * C + c0 + lc];
        __syncthreads();
#pragma unroll
        for (int p = 0; p < 4; ++p) {
            __hip_bfloat16 bv = __float2bfloat16(tile[lc][lr + p * 8]);
            dst[(size_t)(c0 + lr + p * 8) * R + r0 + lc] = *(unsigned short*)&bv;
        }
    }
}

// ---- Kernel A: Wh -> whT bf16 (permuted j) + si/sj (x log2e) — r13 exact ---
__global__ __launch_bounds__(256) void k_wh(
    const float* __restrict__ hin, const float* __restrict__ W,
    const float* __restrict__ a,
    unsigned short* __restrict__ whT, float* __restrict__ si_g,
    float* __restrict__ sj_g)
{
    extern __shared__ float smem[];
    float* h_s  = smem;             // 32 * 132
    float* wt_s = smem + 32 * 132;  // 128 * 132
    int t = threadIdx.x;
    int blk = blockIdx.x;
    int b = blk >> 5;
    int ntile = blk & 31;
    const float* hrow = hin + ((size_t)b * NN + ntile * 32) * IN_DIM;

#pragma unroll
    for (int it = 0; it < 4; ++it) {
        int g = t + 256 * it;
        int row = g >> 5, c4 = g & 31;
        float4 v = ((const float4*)hrow)[g];
        *(float4*)&h_s[row * 132 + c4 * 4] = v;
    }
    for (int g = t; g < (NHEAD * IN_DIM * HD) / 4; g += 256) {
        int hh = g >> 9;
        int rem = g & 511;
        int i = rem >> 2, d4 = rem & 3;
        float4 v = ((const float4*)W)[g];
        wt_s[(hh * 16 + d4 * 4 + 0) * 132 + i] = v.x;
        wt_s[(hh * 16 + d4 * 4 + 1) * 132 + i] = v.y;
        wt_s[(hh * 16 + d4 * 4 + 2) * 132 + i] = v.z;
        wt_s[(hh * 16 + d4 * 4 + 3) * 132 + i] = v.w;
    }
    __syncthreads();

    int d4 = t & 3;
    int hq = (t >> 2) & 7;
    int ngrp = t >> 5;
    float acc[4][4];
#pragma unroll
    for (int q = 0; q < 4; ++q)
#pragma unroll
        for (int dd = 0; dd < 4; ++dd) acc[q][dd] = 0.f;

    for (int i4 = 0; i4 < 32; ++i4) {
        float4 wr[4], hv[4];
#pragma unroll
        for (int dd = 0; dd < 4; ++dd)
            wr[dd] = *(const float4*)&wt_s[(hq * 16 + d4 * 4 + dd) * 132 + i4 * 4];
#pragma unroll
        for (int q = 0; q < 4; ++q)
            hv[q] = *(const float4*)&h_s[(ngrp * 4 + q) * 132 + i4 * 4];
#pragma unroll
        for (int q = 0; q < 4; ++q)
#pragma unroll
            for (int dd = 0; dd < 4; ++dd)
                acc[q][dd] += hv[q].x * wr[dd].x + hv[q].y * wr[dd].y +
                              hv[q].z * wr[dd].z + hv[q].w * wr[dd].w;
    }

    int bh = b * NHEAD + hq;
    int rowbase = ntile * 32 + ngrp * 4;
    int p0 = ((rowbase >> 8) << 8) | ((rowbase >> 2) & 63);

    float asrc[4], adst[4];
#pragma unroll
    for (int dd = 0; dd < 4; ++dd) {
        asrc[dd] = a[hq * 32 + d4 * 4 + dd];
        adst[dd] = a[hq * 32 + 16 + d4 * 4 + dd];
    }
#pragma unroll
    for (int q = 0; q < 4; ++q) {
        float psi = acc[q][0] * asrc[0] + acc[q][1] * asrc[1] + acc[q][2] * asrc[2] + acc[q][3] * asrc[3];
        float psj = acc[q][0] * adst[0] + acc[q][1] * adst[1] + acc[q][2] * adst[2] + acc[q][3] * adst[3];
        psi += __shfl_xor(psi, 1); psi += __shfl_xor(psi, 2);
        psj += __shfl_xor(psj, 1); psj += __shfl_xor(psj, 2);
        if (d4 == 0) {
            si_g[(size_t)bh * NN + rowbase + q] = psi * LOG2E;
            sj_g[(size_t)bh * NN + p0 + q * 64] = psj * LOG2E;
        }
    }

#pragma unroll
    for (int dd = 0; dd < 4; ++dd) {
        unsigned u0, u1;
        asm("v_cvt_pk_bf16_f32 %0, %1, %2" : "=v"(u0) : "v"(acc[0][dd]), "v"(acc[1][dd]));
        asm("v_cvt_pk_bf16_f32 %0, %1, %2" : "=v"(u1) : "v"(acc[2][dd]), "v"(acc[3][dd]));
        size_t basei = (size_t)(bh * 16 + d4 * 4 + dd) * 1024 + p0;
        whT[basei]       = (unsigned short)(u0 & 0xffff);
        whT[basei + 64]  = (unsigned short)(u0 >> 16);
        whT[basei + 128] = (unsigned short)(u1 & 0xffff);
        whT[basei + 192] = (unsigned short)(u1 >> 16);
    }
}

// ---- Kernel B: attention per (b,h) — exp-free softmax, lean loop (r15) -----
__global__ __launch_bounds__(512, 3) void k_attn(
    const unsigned short* __restrict__ whT,
    const unsigned* __restrict__ bits_t,
    const float* __restrict__ si_g, const float* __restrict__ sj_g,
    float* __restrict__ hh)
{
    __shared__ __align__(16) unsigned short whT_s[16 * 1032];
    __shared__ __align__(16) float ejp_s[NN];
    __shared__ __align__(16) float ejn_s[NN];
    int t = threadIdx.x;
    int blk = blockIdx.x;
    int part = blk & 7;
    int bh = blk >> 3;
    int hq = bh & 7, b = bh >> 3;
    int blkrow = part * 128;

    {
        const uint4* src = (const uint4*)(whT + (size_t)bh * 16 * 1024);
#pragma unroll
        for (int it = 0; it < 4; ++it) {
            int g = t + 512 * it;
            int d = g >> 7, c8 = g & 127;
            uint4 v = src[g];
            *(uint4*)&whT_s[d * 1032 + c8 * 8] = v;
        }
#pragma unroll
        for (int jt = 0; jt < 2; ++jt) {
            int j = t + jt * 512;
            float sjv = sj_g[(size_t)bh * NN + j];
            float ep, en;
            asm("v_exp_f32 %0, %1" : "=v"(ep) : "v"(sjv));
            asm("v_exp_f32 %0, %1" : "=v"(en) : "v"(0.2f * sjv));
            ejp_s[j] = ep;
            ejn_s[j] = en;
        }
    }
    __syncthreads();

    int wv = t >> 6, lane = t & 63;
    int lo16 = lane & 15, g = lane >> 4;
    int row = blkrow + wv * 16 + lo16;
    float siL = si_g[(size_t)bh * NN + row];
    float esip, esin;
    asm("v_exp_f32 %0, %1" : "=v"(esip) : "v"(siL));
    asm("v_exp_f32 %0, %1" : "=v"(esin) : "v"(0.2f * siL));
    const unsigned* mcol = bits_t + (size_t)b * 32 * 1024 + row;

    const unsigned short* wbase = &whT_s[lo16 * 1032 + g * 8];
    const float* pbase = &ejp_s[g * 8];
    const float* nbase = &ejn_s[g * 8];

    f32x4 acc = {0.f, 0.f, 0.f, 0.f};
    float lsA = 0.f, lsB = 0.f;
    unsigned m = mcol[0];
#pragma unroll 4
    for (int kt = 0; kt < 32; ++kt) {
        unsigned m_next = (kt < 31) ? mcol[(size_t)(kt + 1) * 1024] : 0u;
        bf16x8 bfrag = *(const bf16x8*)&wbase[kt * 32];
        float4 pa = *(const float4*)&pbase[kt * 32];
        float4 pb = *(const float4*)&pbase[kt * 32 + 4];
        float4 na = *(const float4*)&nbase[kt * 32];
        float4 nb = *(const float4*)&nbase[kt * 32 + 4];
        unsigned mm = m >> (g * 8);
        float q0 = fmaxf(esip * pa.x, esin * na.x); q0 = (mm & 1u)   ? q0 : 0.f;
        float q1 = fmaxf(esip * pa.y, esin * na.y); q1 = (mm & 2u)   ? q1 : 0.f;
        float q2 = fmaxf(esip * pa.z, esin * na.z); q2 = (mm & 4u)   ? q2 : 0.f;
        float q3 = fmaxf(esip * pa.w, esin * na.w); q3 = (mm & 8u)   ? q3 : 0.f;
        float q4 = fmaxf(esip * pb.x, esin * nb.x); q4 = (mm & 16u)  ? q4 : 0.f;
        float q5 = fmaxf(esip * pb.y, esin * nb.y); q5 = (mm & 32u)  ? q5 : 0.f;
        float q6 = fmaxf(esip * pb.z, esin * nb.z); q6 = (mm & 64u)  ? q6 : 0.f;
        float q7 = fmaxf(esip * pb.w, esin * nb.w); q7 = (mm & 128u) ? q7 : 0.f;
        lsA += (q0 + q2) + (q4 + q6);
        lsB += (q1 + q3) + (q5 + q7);
        union { bf16x8 v; __hip_bfloat16 h[8]; } af;
        af.h[0] = __float2bfloat16(q0);
        af.h[1] = __float2bfloat16(q1);
        af.h[2] = __float2bfloat16(q2);
        af.h[3] = __float2bfloat16(q3);
        af.h[4] = __float2bfloat16(q4);
        af.h[5] = __float2bfloat16(q5);
        af.h[6] = __float2bfloat16(q6);
        af.h[7] = __float2bfloat16(q7);
        acc = __builtin_amdgcn_mfma_f32_16x16x32_bf16(af.v, bfrag, acc, 0, 0, 0);
        m = m_next;
    }

    float lsum = lsA + lsB;
    lsum += __shfl_xor(lsum, 16);
    lsum += __shfl_xor(lsum, 32);

    float* obase = hh + ((size_t)b * NN + blkrow + wv * 16) * OUT_DIM + hq * HD + lo16;
#pragma unroll
    for (int q = 0; q < 4; ++q) {
        float ls = __shfl(lsum, 4 * g + q);
        float r = (ls > 0.f) ? 1.0f / ls : 0.f;
        obase[(size_t)(4 * g + q) * OUT_DIM] = acc[q] * r;
    }
}

// -------- Kernel C: LN1 + FFN (MFMA bf16) + LN2 — r6/r8 exact ----------
__global__ __launch_bounds__(512, 1) void k_ffn(const float* __restrict__ hhs,
                                                const float* __restrict__ hin,
                                                const float* __restrict__ g1,
                                                const float* __restrict__ bt1,
                                                const unsigned short* __restrict__ w1T,
                                                const float* __restrict__ bb1,
                                                const unsigned short* __restrict__ w2T,
                                                const float* __restrict__ bb2,
                                                const float* __restrict__ g2,
                                                const float* __restrict__ bt2,
                                                float* __restrict__ out) {
    __shared__ float xc_f[32][128];
    __shared__ float y_f[32][132];
    __shared__ __align__(16) unsigned short xc_bf[32 * 128];
    __shared__ __align__(16) unsigned short hid_bf[32 * 256];

    int t = threadIdx.x;
    int R0 = blockIdx.x * 32;
    int wv = t >> 6, lane = t & 63;
    int lo = lane & 15, g = lane >> 4;

    bf16x8 b1f[2][4];
#pragma unroll
    for (int jt = 0; jt < 2; ++jt) {
        int n = (wv * 2 + jt) * 16 + lo;
#pragma unroll
        for (int kt = 0; kt < 4; ++kt)
            b1f[jt][kt] = *(const bf16x8*)&w1T[(size_t)n * 128 + kt * 32 + g * 8];
    }
    bf16x8 b2f[8];
    {
        int n = wv * 16 + lo;
#pragma unroll
        for (int kt = 0; kt < 8; ++kt)
            b2f[kt] = *(const bf16x8*)&w2T[(size_t)n * 256 + kt * 32 + g * 8];
    }
    float b1v[2];
    b1v[0] = bb1[(wv * 2 + 0) * 16 + lo];
    b1v[1] = bb1[(wv * 2 + 1) * 16 + lo];
    float b2v = bb2[wv * 16 + lo];

    {
        int r = t >> 4, c = t & 15;
        size_t row = (size_t)(R0 + r) * 128;
        float4 ha = *(const float4*)&hhs[row + c * 8];
        float4 hb = *(const float4*)&hhs[row + c * 8 + 4];
        float4 ia = *(const float4*)&hin[row + c * 8];
        float4 ib = *(const float4*)&hin[row + c * 8 + 4];
        float x[8] = {ha.x + ia.x, ha.y + ia.y, ha.z + ia.z, ha.w + ia.w,
                      hb.x + ib.x, hb.y + ib.y, hb.z + ib.z, hb.w + ib.w};
        float s = 0.f, s2 = 0.f;
#pragma unroll
        for (int j = 0; j < 8; ++j) { s += x[j]; s2 += x[j] * x[j]; }
#pragma unroll
        for (int off = 8; off > 0; off >>= 1) {
            s += __shfl_xor(s, off);
            s2 += __shfl_xor(s2, off);
        }
        float mu = s * (1.f / 128.f);
        float var = s2 * (1.f / 128.f) - mu * mu;
        float rs = rsqrtf(var + 1e-5f);
        float4 ga = *(const float4*)&g1[c * 8], gb = *(const float4*)&g1[c * 8 + 4];
        float4 ba = *(const float4*)&bt1[c * 8], bb = *(const float4*)&bt1[c * 8 + 4];
        float gg[8] = {ga.x, ga.y, ga.z, ga.w, gb.x, gb.y, gb.z, gb.w};
        float bbv[8] = {ba.x, ba.y, ba.z, ba.w, bb.x, bb.y, bb.z, bb.w};
        float xo[8];
#pragma unroll
        for (int j = 0; j < 8; ++j) xo[j] = (x[j] - mu) * rs * gg[j] + bbv[j];
        *(float4*)&xc_f[r][c * 8]     = make_float4(xo[0], xo[1], xo[2], xo[3]);
        *(float4*)&xc_f[r][c * 8 + 4] = make_float4(xo[4], xo[5], xo[6], xo[7]);
        union { uint4 v; unsigned u[4]; } pk;
#pragma unroll
        for (int q = 0; q < 4; ++q)
            asm("v_cvt_pk_bf16_f32 %0, %1, %2" : "=v"(pk.u[q]) : "v"(xo[2 * q]), "v"(xo[2 * q + 1]));
        int byte = (r * 256 + c * 16) ^ ((r & 7) << 4);
        *(uint4*)((char*)xc_bf + byte) = pk.v;
    }
    __syncthreads();

    {
        bf16x8 af[2][4];
#pragma unroll
        for (int mt = 0; mt < 2; ++mt) {
            int m = mt * 16 + lo;
#pragma unroll
            for (int kt = 0; kt < 4; ++kt) {
                int byte = (m * 256 + kt * 64 + g * 16) ^ ((m & 7) << 4);
                af[mt][kt] = *(const bf16x8*)((const char*)xc_bf + byte);
            }
        }
#pragma unroll
        for (int mt = 0; mt < 2; ++mt)
#pragma unroll
            for (int jt = 0; jt < 2; ++jt) {
                f32x4 acc = {0.f, 0.f, 0.f, 0.f};
#pragma unroll
                for (int kt = 0; kt < 4; ++kt)
                    acc = __builtin_amdgcn_mfma_f32_16x16x32_bf16(af[mt][kt], b1f[jt][kt], acc, 0, 0, 0);
                int n = (wv * 2 + jt) * 16 + lo;
#pragma unroll
                for (int q = 0; q < 4; ++q) {
                    float hv = fmaxf(acc[q] + b1v[jt], 0.f);
                    int m = mt * 16 + 4 * g + q;
                    int byte = (m * 512 + n * 2) ^ ((m & 7) << 4);
                    __hip_bfloat16 bv = __float2bfloat16(hv);
                    *(unsigned short*)((char*)hid_bf + byte) = *(unsigned short*)&bv;
                }
            }
    }
    __syncthreads();

    {
        f32x4 acc2[2] = {{0.f, 0.f, 0.f, 0.f}, {0.f, 0.f, 0.f, 0.f}};
#pragma unroll
        for (int mt = 0; mt < 2; ++mt) {
            int m = mt * 16 + lo;
#pragma unroll
            for (int kt = 0; kt < 8; ++kt) {
                int byte = (m * 512 + kt * 64 + g * 16) ^ ((m & 7) << 4);
                bf16x8 a = *(const bf16x8*)((const char*)hid_bf + byte);
                acc2[mt] = __builtin_amdgcn_mfma_f32_16x16x32_bf16(a, b2f[kt], acc2[mt], 0, 0, 0);
            }
        }
        int n = wv * 16 + lo;
#pragma unroll
        for (int mt = 0; mt < 2; ++mt)
#pragma unroll
            for (int q = 0; q < 4; ++q)
                y_f[mt * 16 + 4 * g + q][n] = acc2[mt][q] + b2v;
    }
    __syncthreads();

    {
        int r = t >> 4, c = t & 15;
        float xv[8];
        float s = 0.f, s2 = 0.f;
#pragma unroll
        for (int j = 0; j < 8; ++j) {
            float v = xc_f[r][c * 8 + j] + y_f[r][c * 8 + j];
            xv[j] = v; s += v; s2 += v * v;
        }
#pragma unroll
        for (int off = 8; off > 0; off >>= 1) {
            s += __shfl_xor(s, off);
            s2 += __shfl_xor(s2, off);
        }
        float mu = s * (1.f / 128.f);
        float var = s2 * (1.f / 128.f) - mu * mu;
        float rs = rsqrtf(var + 1e-5f);
        float4 ga = *(const float4*)&g2[c * 8], gb = *(const float4*)&g2[c * 8 + 4];
        float4 ba = *(const float4*)&bt2[c * 8], bb = *(const float4*)&bt2[c * 8 + 4];
        float o[8] = {(xv[0] - mu) * rs * ga.x + ba.x, (xv[1] - mu) * rs * ga.y + ba.y,
                      (xv[2] - mu) * rs * ga.z + ba.z, (xv[3] - mu) * rs * ga.w + ba.w,
                      (xv[4] - mu) * rs * gb.x + bb.x, (xv[5] - mu) * rs * gb.y + bb.y,
                      (xv[6] - mu) * rs * gb.z + bb.z, (xv[7] - mu) * rs * gb.w + bb.w};
        size_t row = (size_t)(R0 + r) * 128;
        *(float4*)&out[row + c * 8]     = make_float4(o[0], o[1], o[2], o[3]);
        *(float4*)&out[row + c * 8 + 4] = make_float4(o[4], o[5], o[6], o[7]);
    }
}

extern "C" void kernel_launch(void* const* d_in, const int* in_sizes, int n_in,
                              void* d_out, int out_size, void* d_ws, size_t ws_size,
                              hipStream_t stream) {
    const float* hin  = (const float*)d_in[0];
    const int*   adj  = (const int*)d_in[1];
    const float* W    = (const float*)d_in[2];
    const float* a    = (const float*)d_in[3];
    const float* ln1g = (const float*)d_in[4];
    const float* ln1b = (const float*)d_in[5];
    const float* w1   = (const float*)d_in[6];
    const float* b1   = (const float*)d_in[7];
    const float* w2   = (const float*)d_in[8];
    const float* b2   = (const float*)d_in[9];
    const float* ln2g = (const float*)d_in[10];
    const float* ln2b = (const float*)d_in[11];
    float* out = (float*)d_out;

    unsigned* bits_t    = (unsigned*)d_ws;                                         // 1 MB
    unsigned short* whT = (unsigned short*)((char*)d_ws + (1u << 20));             // 2 MB
    float* si_g         = (float*)((char*)d_ws + (3u << 20));                      // 256 KB
    float* sj_g         = (float*)((char*)d_ws + (3u << 20) + (256u << 10));       // 256 KB
    float* hh           = (float*)((char*)d_ws + (3u << 20) + (512u << 10));       // 4 MB
    unsigned short* w1T = (unsigned short*)((char*)d_ws + (7u << 20) + (512u << 10));        // 64 KB
    unsigned short* w2T = (unsigned short*)((char*)d_ws + (7u << 20) + (512u << 10) + 65536);// 64 KB

    k_pack<<<2112, 256, 0, stream>>>(adj, bits_t, w1, w2, w1T, w2T);
    k_wh<<<BB * 32, 256, (32 * 132 + 128 * 132) * sizeof(float), stream>>>(hin, W, a, whT, si_g, sj_g);
    k_attn<<<BB * NHEAD * 8, 512, 0, stream>>>(whT, bits_t, si_g, sj_g, hh);
    k_ffn<<<BB * NN / 32, 512, 0, stream>>>(hh, hin, ln1g, ln1b, w1T, b1, w2T, b2, ln2g, ln2b, out);
}